// Round 3
// baseline (826.862 us; speedup 1.0000x reference)
//
#include <hip/hip_runtime.h>

#define HID 128
#define NNODES 50000
#define NEDGES 800000
#define NGRAPHS 64
#define NLAYERS 2
#define BN_EPS 1e-5f

// ---------------------------------------------------------------------------
__global__ __launch_bounds__(128) void embed_kernel(
    const int* __restrict__ x_idx, const float* __restrict__ node_emb,
    float* __restrict__ x) {
  int n = blockIdx.x;
  int c = threadIdx.x;
  x[n * HID + c] = node_emb[x_idx[n] * HID + c];
}

// ===========================================================================
// CSR build: histogram -> scan -> scatter (rebuilt every call, deterministic
// structure; within-node edge order is nondeterministic -> fp32 rounding only)
// ===========================================================================
__global__ __launch_bounds__(256) void deg_kernel(
    const int* __restrict__ eidx, int* __restrict__ deg) {
  int e = blockIdx.x * 256 + threadIdx.x;
  if (e < NEDGES) atomicAdd(&deg[eidx[NEDGES + e]], 1);
}

#define SCAN_CHUNK 196  // 256*196 = 50176 >= 50000
__global__ __launch_bounds__(256) void scan1_kernel(
    const int* __restrict__ deg, int* __restrict__ chunk_base) {
  __shared__ int s[256];
  int t = threadIdx.x;
  int sum = 0;
  int base = t * SCAN_CHUNK;
  #pragma unroll 4
  for (int i = 0; i < SCAN_CHUNK; i++) {
    int idx = base + i;
    sum += (idx < NNODES) ? deg[idx] : 0;
  }
  s[t] = sum;
  __syncthreads();
  for (int off = 1; off < 256; off <<= 1) {
    int v = (t >= off) ? s[t - off] : 0;
    __syncthreads();
    s[t] += v;
    __syncthreads();
  }
  chunk_base[t] = s[t] - sum;  // exclusive
}

__global__ __launch_bounds__(256) void scan2_kernel(
    const int* __restrict__ deg, const int* __restrict__ chunk_base,
    int* __restrict__ offs, int* __restrict__ cursor) {
  __shared__ int s[256];
  int b = blockIdx.x;
  int t = threadIdx.x;
  int idx = b * SCAN_CHUNK + t;
  int val = (t < SCAN_CHUNK && idx < NNODES) ? deg[idx] : 0;
  s[t] = val;
  __syncthreads();
  for (int off = 1; off < 256; off <<= 1) {
    int v = (t >= off) ? s[t - off] : 0;
    __syncthreads();
    s[t] += v;
    __syncthreads();
  }
  if (t < SCAN_CHUNK && idx < NNODES) {
    int excl = chunk_base[b] + s[t] - val;
    offs[idx] = excl;
    cursor[idx] = excl;
  }
  if (b == 0 && t == 0) offs[NNODES] = NEDGES;
}

__global__ __launch_bounds__(256) void scatter_kernel(
    const int* __restrict__ eidx, const int* __restrict__ eattr,
    int* __restrict__ cursor, int* __restrict__ eout) {
  int e = blockIdx.x * 256 + threadIdx.x;
  if (e >= NEDGES) return;
  int d = eidx[NEDGES + e];
  int pos = atomicAdd(&cursor[d], 1);
  eout[pos] = eidx[e] | (eattr[e] << 16);  // src<65536, attr<4
}

// ---------------------------------------------------------------------------
// wt[m][c][k] = W_m[k][c] ; m = layer*2 + {0:W1,1:W2}
__global__ __launch_bounds__(128) void wtrans_kernel(
    const float* __restrict__ W1, const float* __restrict__ W2,
    float* __restrict__ wt) {
  int k = blockIdx.x;  // 0..127
  int m = blockIdx.y;  // 0..3
  int c = threadIdx.x;
  const float* src = (m & 1) ? W2 : W1;
  int l = m >> 1;
  wt[((size_t)m * HID + c) * HID + k] = src[((size_t)l * HID + k) * HID + c];
}

// ===========================================================================
// Fused GINE layer. block = (64,4): thread owns 2 channels (x, x+64) and the
// 4 nodes of its y-slice. Optional input BN folded in as per-channel affine.
// ===========================================================================
#define NB 16
#define NGROUPS (NNODES / NB)  // 3125 exact
#define GRID_GINE 1563         // 2 groups per block (block 1562 does 1)

__global__ __launch_bounds__(256) void gine_mlp_kernel(
    const float* __restrict__ in, const float* __restrict__ instats,
    const float* __restrict__ gam, const float* __restrict__ bet,
    const int* __restrict__ offs, const int* __restrict__ eout,
    const float* __restrict__ edge_emb,
    const float* __restrict__ W1T, const float* __restrict__ b1,
    const float* __restrict__ W2T, const float* __restrict__ b2,
    float* __restrict__ h2, float* __restrict__ stats) {
  __shared__ __align__(16) float hA[NB * HID];
  __shared__ __align__(16) float hB[NB * HID];
  const int cx = threadIdx.x;       // 0..63
  const int y = threadIdx.y;        // 0..3
  const int c0 = cx, c1 = cx + 64;

  // input affine (BN of previous layer, or identity)
  float scl0 = 1.0f, sh0 = 0.0f, scl1 = 1.0f, sh1 = 0.0f;
  if (instats) {
    float mu0 = instats[c0] * (1.0f / NNODES);
    float va0 = instats[HID + c0] * (1.0f / NNODES) - mu0 * mu0;
    scl0 = gam[c0] * rsqrtf(va0 + BN_EPS);
    sh0 = bet[c0] - mu0 * scl0;
    float mu1 = instats[c1] * (1.0f / NNODES);
    float va1 = instats[HID + c1] * (1.0f / NNODES) - mu1 * mu1;
    scl1 = gam[c1] * rsqrtf(va1 + BN_EPS);
    sh1 = bet[c1] - mu1 * scl1;
  }
  // she[a] = sh + edge_emb[a]  (message = relu(scl*x_raw + she[a]))
  float she00 = sh0 + edge_emb[0 * HID + c0];
  float she01 = sh0 + edge_emb[1 * HID + c0];
  float she02 = sh0 + edge_emb[2 * HID + c0];
  float she03 = sh0 + edge_emb[3 * HID + c0];
  float she10 = sh1 + edge_emb[0 * HID + c1];
  float she11 = sh1 + edge_emb[1 * HID + c1];
  float she12 = sh1 + edge_emb[2 * HID + c1];
  float she13 = sh1 + edge_emb[3 * HID + c1];

  float bias10 = b1[c0], bias11 = b1[c1];
  float bias20 = b2[c0], bias21 = b2[c1];

  float lsum0 = 0.0f, lsum1 = 0.0f, lsq0 = 0.0f, lsq1 = 0.0f;
  const float4* W1T4 = (const float4*)W1T;
  const float4* W2T4 = (const float4*)W2T;
  const float4* hA4 = (const float4*)hA;
  const float4* hB4 = (const float4*)hB;

  for (int g = blockIdx.x; g < NGROUPS; g += GRID_GINE) {
    int base = g * NB;
    // ---- gather: h0 = affine(x_self) + sum relu(affine(x_src)+e) ----
    #pragma unroll
    for (int i = 0; i < 4; i++) {
      int n = y * 4 + i;
      int node = base + n;
      float v0 = fmaf(in[node * HID + c0], scl0, sh0);
      float v1 = fmaf(in[node * HID + c1], scl1, sh1);
      int e = offs[node], e1 = offs[node + 1];
      for (; e + 2 <= e1; e += 2) {
        int p0 = eout[e], p1 = eout[e + 1];
        int s0 = p0 & 0xFFFF, a0 = p0 >> 16;
        int s1 = p1 & 0xFFFF, a1 = p1 >> 16;
        float xa0 = in[s0 * HID + c0];
        float xb0 = in[s0 * HID + c1];
        float xa1 = in[s1 * HID + c0];
        float xb1 = in[s1 * HID + c1];
        float sA0 = (a0 == 0) ? she00 : (a0 == 1) ? she01 : (a0 == 2) ? she02 : she03;
        float sB0 = (a0 == 0) ? she10 : (a0 == 1) ? she11 : (a0 == 2) ? she12 : she13;
        float sA1 = (a1 == 0) ? she00 : (a1 == 1) ? she01 : (a1 == 2) ? she02 : she03;
        float sB1 = (a1 == 0) ? she10 : (a1 == 1) ? she11 : (a1 == 2) ? she12 : she13;
        v0 += fmaxf(fmaf(xa0, scl0, sA0), 0.0f) + fmaxf(fmaf(xa1, scl0, sA1), 0.0f);
        v1 += fmaxf(fmaf(xb0, scl1, sB0), 0.0f) + fmaxf(fmaf(xb1, scl1, sB1), 0.0f);
      }
      if (e < e1) {
        int p0 = eout[e];
        int s0 = p0 & 0xFFFF, a0 = p0 >> 16;
        float sA0 = (a0 == 0) ? she00 : (a0 == 1) ? she01 : (a0 == 2) ? she02 : she03;
        float sB0 = (a0 == 0) ? she10 : (a0 == 1) ? she11 : (a0 == 2) ? she12 : she13;
        v0 += fmaxf(fmaf(in[s0 * HID + c0], scl0, sA0), 0.0f);
        v1 += fmaxf(fmaf(in[s0 * HID + c1], scl1, sB0), 0.0f);
      }
      hA[n * HID + c0] = v0;
      hA[n * HID + c1] = v1;
    }
    __syncthreads();

    // ---- GEMM1: hB = relu(hA @ W1 + b1) ----
    float acc0[4], acc1[4];
    #pragma unroll
    for (int i = 0; i < 4; i++) { acc0[i] = bias10; acc1[i] = bias11; }
    for (int k4 = 0; k4 < HID / 4; k4++) {
      float4 w0 = W1T4[c0 * (HID / 4) + k4];
      float4 w1 = W1T4[c1 * (HID / 4) + k4];
      #pragma unroll
      for (int i = 0; i < 4; i++) {
        float4 a = hA4[(y * 4 + i) * (HID / 4) + k4];
        acc0[i] = fmaf(a.x, w0.x, acc0[i]);
        acc0[i] = fmaf(a.y, w0.y, acc0[i]);
        acc0[i] = fmaf(a.z, w0.z, acc0[i]);
        acc0[i] = fmaf(a.w, w0.w, acc0[i]);
        acc1[i] = fmaf(a.x, w1.x, acc1[i]);
        acc1[i] = fmaf(a.y, w1.y, acc1[i]);
        acc1[i] = fmaf(a.z, w1.z, acc1[i]);
        acc1[i] = fmaf(a.w, w1.w, acc1[i]);
      }
    }
    #pragma unroll
    for (int i = 0; i < 4; i++) {
      int n = y * 4 + i;
      hB[n * HID + c0] = fmaxf(acc0[i], 0.0f);
      hB[n * HID + c1] = fmaxf(acc1[i], 0.0f);
    }
    __syncthreads();

    // ---- GEMM2: h2 = relu(hB @ W2 + b2); stats accumulate ----
    #pragma unroll
    for (int i = 0; i < 4; i++) { acc0[i] = bias20; acc1[i] = bias21; }
    for (int k4 = 0; k4 < HID / 4; k4++) {
      float4 w0 = W2T4[c0 * (HID / 4) + k4];
      float4 w1 = W2T4[c1 * (HID / 4) + k4];
      #pragma unroll
      for (int i = 0; i < 4; i++) {
        float4 a = hB4[(y * 4 + i) * (HID / 4) + k4];
        acc0[i] = fmaf(a.x, w0.x, acc0[i]);
        acc0[i] = fmaf(a.y, w0.y, acc0[i]);
        acc0[i] = fmaf(a.z, w0.z, acc0[i]);
        acc0[i] = fmaf(a.w, w0.w, acc0[i]);
        acc1[i] = fmaf(a.x, w1.x, acc1[i]);
        acc1[i] = fmaf(a.y, w1.y, acc1[i]);
        acc1[i] = fmaf(a.z, w1.z, acc1[i]);
        acc1[i] = fmaf(a.w, w1.w, acc1[i]);
      }
    }
    #pragma unroll
    for (int i = 0; i < 4; i++) {
      int n = y * 4 + i;
      int node = base + n;
      float v0 = fmaxf(acc0[i], 0.0f);
      float v1 = fmaxf(acc1[i], 0.0f);
      h2[node * HID + c0] = v0;
      h2[node * HID + c1] = v1;
      lsum0 += v0; lsq0 += v0 * v0;
      lsum1 += v1; lsq1 += v1 * v1;
    }
    __syncthreads();  // protect hA (gather of g+1) & hB (GEMM1 of g+1)
  }

  // ---- block-level stats reduction (reuse hA/hB as scratch) ----
  hA[y * HID + c0] = lsum0;
  hA[y * HID + c1] = lsum1;
  hB[y * HID + c0] = lsq0;
  hB[y * HID + c1] = lsq1;
  __syncthreads();
  if (y == 0) {
    float s0 = hA[c0] + hA[HID + c0] + hA[2 * HID + c0] + hA[3 * HID + c0];
    float s1 = hA[c1] + hA[HID + c1] + hA[2 * HID + c1] + hA[3 * HID + c1];
    float q0 = hB[c0] + hB[HID + c0] + hB[2 * HID + c0] + hB[3 * HID + c0];
    float q1 = hB[c1] + hB[HID + c1] + hB[2 * HID + c1] + hB[3 * HID + c1];
    unsafeAtomicAdd(&stats[c0], s0);
    unsafeAtomicAdd(&stats[c1], s1);
    unsafeAtomicAdd(&stats[HID + c0], q0);
    unsafeAtomicAdd(&stats[HID + c1], q1);
  }
}

// ---------------------------------------------------------------------------
// Final BN + global_add_pool fused (never materializes BN-ed x).
#define PNB 200
__global__ __launch_bounds__(128) void bn_pool_kernel(
    const float* __restrict__ h, const float* __restrict__ stats,
    const float* __restrict__ gam, const float* __restrict__ bet,
    const int* __restrict__ batch, float* __restrict__ out) {
  int c = threadIdx.x;
  float mu = stats[c] * (1.0f / NNODES);
  float var = stats[HID + c] * (1.0f / NNODES) - mu * mu;
  float scl = gam[c] * rsqrtf(var + BN_EPS);
  float sh = bet[c] - mu * scl;
  int n0 = blockIdx.x * PNB;
  int n1 = min(n0 + PNB, NNODES);
  if (n0 >= NNODES) return;
  int cur = batch[n0];
  float acc = 0.0f;
  for (int n = n0; n < n1; n++) {
    int g = batch[n];
    if (g != cur) {
      unsafeAtomicAdd(&out[cur * HID + c], acc);
      acc = 0.0f;
      cur = g;
    }
    acc += fmaf(h[n * HID + c], scl, sh);
  }
  unsafeAtomicAdd(&out[cur * HID + c], acc);
}

// ---------------------------------------------------------------------------
// Fallback path kernels (atomic scatter) — only if ws_size too small.
#define EPB 16
__global__ __launch_bounds__(256) void edge_kernel(
    const int* __restrict__ eidx, const int* __restrict__ eattr,
    const float* __restrict__ x, const float* __restrict__ edge_emb,
    float* __restrict__ aggr) {
  int c = threadIdx.x;
  int e0 = blockIdx.x * EPB;
  for (int e = e0 + (int)threadIdx.y; e < e0 + EPB; e += 2) {
    int s = eidx[e];
    int d = eidx[NEDGES + e];
    int a = eattr[e];
    float v = fmaxf(x[s * HID + c] + edge_emb[a * HID + c], 0.0f);
    unsafeAtomicAdd(&aggr[d * HID + c], v);
  }
}

#define FNB 8
__global__ __launch_bounds__(128) void mlp_kernel(
    const float* __restrict__ x, float* __restrict__ aggr,
    const float* __restrict__ W1, const float* __restrict__ b1,
    const float* __restrict__ W2, const float* __restrict__ b2,
    float* __restrict__ stats) {
  __shared__ float hA[FNB * HID];
  __shared__ float hB[FNB * HID];
  int c = threadIdx.x;
  float lsum = 0.0f, lsq = 0.0f;
  const int ngroups = (NNODES + FNB - 1) / FNB;
  float bias1 = b1[c];
  float bias2 = b2[c];
  for (int g = blockIdx.x; g < ngroups; g += gridDim.x) {
    int base = g * FNB;
    #pragma unroll
    for (int n = 0; n < FNB; n++) {
      int node = base + n;
      float v = 0.0f;
      if (node < NNODES) v = x[node * HID + c] + aggr[node * HID + c];
      hA[n * HID + c] = v;
    }
    __syncthreads();
    float acc[FNB];
    #pragma unroll
    for (int n = 0; n < FNB; n++) acc[n] = bias1;
    for (int k = 0; k < HID; k++) {
      float w = W1[k * HID + c];
      #pragma unroll
      for (int n = 0; n < FNB; n++) acc[n] = fmaf(hA[n * HID + k], w, acc[n]);
    }
    #pragma unroll
    for (int n = 0; n < FNB; n++) hB[n * HID + c] = fmaxf(acc[n], 0.0f);
    __syncthreads();
    #pragma unroll
    for (int n = 0; n < FNB; n++) acc[n] = bias2;
    for (int k = 0; k < HID; k++) {
      float w = W2[k * HID + c];
      #pragma unroll
      for (int n = 0; n < FNB; n++) acc[n] = fmaf(hB[n * HID + k], w, acc[n]);
    }
    #pragma unroll
    for (int n = 0; n < FNB; n++) {
      int node = base + n;
      if (node < NNODES) {
        float v = fmaxf(acc[n], 0.0f);
        aggr[node * HID + c] = v;
        lsum += v;
        lsq += v * v;
      }
    }
    __syncthreads();
  }
  unsafeAtomicAdd(&stats[c], lsum);
  unsafeAtomicAdd(&stats[HID + c], lsq);
}

__global__ __launch_bounds__(128) void bn_kernel(
    const float* __restrict__ h, float* __restrict__ x,
    const float* __restrict__ stats, const float* __restrict__ gam,
    const float* __restrict__ bet) {
  int c = threadIdx.x;
  float mu = stats[c] * (1.0f / NNODES);
  float var = stats[HID + c] * (1.0f / NNODES) - mu * mu;
  float scl = gam[c] * rsqrtf(var + BN_EPS);
  float sh = bet[c] - mu * scl;
  for (int n = blockIdx.x; n < NNODES; n += gridDim.x)
    x[n * HID + c] = fmaf(h[n * HID + c], scl, sh);
}

__global__ __launch_bounds__(128) void pool_kernel(
    const float* __restrict__ x, const int* __restrict__ batch,
    float* __restrict__ out) {
  int c = threadIdx.x;
  int n0 = blockIdx.x * PNB;
  int n1 = min(n0 + PNB, NNODES);
  if (n0 >= NNODES) return;
  int cur = batch[n0];
  float acc = 0.0f;
  for (int n = n0; n < n1; n++) {
    int g = batch[n];
    if (g != cur) {
      unsafeAtomicAdd(&out[cur * HID + c], acc);
      acc = 0.0f;
      cur = g;
    }
    acc += x[n * HID + c];
  }
  unsafeAtomicAdd(&out[cur * HID + c], acc);
}

// ---------------------------------------------------------------------------
extern "C" void kernel_launch(void* const* d_in, const int* in_sizes, int n_in,
                              void* d_out, int out_size, void* d_ws, size_t ws_size,
                              hipStream_t stream) {
  const int* x_idx = (const int*)d_in[0];
  const int* eidx = (const int*)d_in[1];   // [2, E]: src row then dst row
  const int* eattr = (const int*)d_in[2];
  const int* batch = (const int*)d_in[3];
  const float* node_emb = (const float*)d_in[4];
  const float* edge_emb = (const float*)d_in[5];
  const float* W1 = (const float*)d_in[6];
  const float* b1 = (const float*)d_in[7];
  const float* W2 = (const float*)d_in[8];
  const float* b2 = (const float*)d_in[9];
  const float* bn_g = (const float*)d_in[10];
  const float* bn_b = (const float*)d_in[11];
  float* out = (float*)d_out;

  const size_t nfeat = (size_t)NNODES * HID;
  float* x = (float*)d_ws;               // [N,H]  (layer-2 h2 reuses this)
  float* h2a = x + nfeat;                // [N,H]
  float* stats0 = h2a + nfeat;           // [2,H]
  float* stats1 = stats0 + 2 * HID;      // [2,H]
  int* deg = (int*)(stats1 + 2 * HID);   // [N]    (zeroed with stats)
  float* wt = (float*)(deg + NNODES);    // [4][H][H]
  int* offs = (int*)(wt + 4 * HID * HID);  // [N+1]
  int* cursor = offs + (NNODES + 1);       // [N]
  int* chunk_base = cursor + NNODES;       // [256]
  int* eout = chunk_base + 256;            // [E]
  size_t needed = (size_t)((char*)(eout + NEDGES) - (char*)d_ws);

  hipMemsetAsync(d_out, 0, (size_t)NGRAPHS * HID * sizeof(float), stream);
  embed_kernel<<<NNODES, 128, 0, stream>>>(x_idx, node_emb, x);

  if (ws_size >= needed) {
    // zero stats0, stats1, deg in one shot (contiguous)
    hipMemsetAsync(stats0, 0, (4 * HID + NNODES) * sizeof(int), stream);
    deg_kernel<<<(NEDGES + 255) / 256, 256, 0, stream>>>(eidx, deg);
    scan1_kernel<<<1, 256, 0, stream>>>(deg, chunk_base);
    scan2_kernel<<<256, 256, 0, stream>>>(deg, chunk_base, offs, cursor);
    scatter_kernel<<<(NEDGES + 255) / 256, 256, 0, stream>>>(eidx, eattr,
                                                             cursor, eout);
    wtrans_kernel<<<dim3(HID, 4), 128, 0, stream>>>(W1, W2, wt);

    // layer 0: in = x (no input BN), out -> h2a, stats -> stats0
    gine_mlp_kernel<<<GRID_GINE, dim3(64, 4), 0, stream>>>(
        x, nullptr, nullptr, nullptr, offs, eout, edge_emb,
        wt + 0 * HID * HID, b1, wt + 1 * HID * HID, b2, h2a, stats0);
    // layer 1: in = h2a with BN(layer0) affine, out -> x, stats -> stats1
    gine_mlp_kernel<<<GRID_GINE, dim3(64, 4), 0, stream>>>(
        h2a, stats0, bn_g, bn_b, offs, eout, edge_emb,
        wt + 2 * HID * HID, b1 + HID, wt + 3 * HID * HID, b2 + HID, x, stats1);
    // final BN + pool fused
    bn_pool_kernel<<<(NNODES + PNB - 1) / PNB, 128, 0, stream>>>(
        x, stats1, bn_g + HID, bn_b + HID, batch, out);
  } else {
    // fallback: atomic-scatter path
    for (int l = 0; l < NLAYERS; l++) {
      hipMemsetAsync(h2a, 0, nfeat * sizeof(float), stream);
      hipMemsetAsync(stats0, 0, 2 * HID * sizeof(float), stream);
      edge_kernel<<<NEDGES / EPB, dim3(128, 2), 0, stream>>>(eidx, eattr, x,
                                                             edge_emb, h2a);
      mlp_kernel<<<2048, 128, 0, stream>>>(
          x, h2a, W1 + (size_t)l * HID * HID, b1 + l * HID,
          W2 + (size_t)l * HID * HID, b2 + l * HID, stats0);
      bn_kernel<<<2048, 128, 0, stream>>>(h2a, x, stats0, bn_g + l * HID,
                                          bn_b + l * HID);
    }
    pool_kernel<<<(NNODES + PNB - 1) / PNB, 128, 0, stream>>>(x, batch, out);
  }
}

// Round 4
// 566.673 us; speedup vs baseline: 1.4592x; 1.4592x over previous
//
#include <hip/hip_runtime.h>

#define HID 128
#define NNODES 50000
#define NEDGES 800000
#define NGRAPHS 64
#define BN_EPS 1e-5f
#define SCAN_CHUNK 196  // 256*196 = 50176 >= 50000

// ===========================================================================
// prep: x = node_emb[x_idx] (float4, grid-stride) + in-degree histogram
// ===========================================================================
__global__ __launch_bounds__(256) void prep_kernel(
    const int* __restrict__ x_idx, const float* __restrict__ node_emb,
    float* __restrict__ x, const int* __restrict__ eidx,
    int* __restrict__ deg) {
  int i = blockIdx.x * 256 + threadIdx.x;
  int stride = gridDim.x * 256;
  const float4* ne4 = (const float4*)node_emb;
  float4* x4 = (float4*)x;
  for (int t = i; t < NNODES * (HID / 4); t += stride) {
    int n = t >> 5;   // HID/4 == 32
    int c4 = t & 31;
    x4[t] = ne4[x_idx[n] * 32 + c4];
  }
  for (int t = i; t < NEDGES; t += stride)
    atomicAdd(&deg[eidx[NEDGES + t]], 1);
}

// ===========================================================================
// CSR build, 3-pass coalesced scan
// ===========================================================================
__global__ __launch_bounds__(256) void chunksum_kernel(
    const int* __restrict__ deg, int* __restrict__ csum) {
  __shared__ int s[256];
  int b = blockIdx.x, t = threadIdx.x;
  int idx = b * SCAN_CHUNK + t;
  int v = (t < SCAN_CHUNK && idx < NNODES) ? deg[idx] : 0;
  s[t] = v;
  __syncthreads();
  for (int off = 128; off > 0; off >>= 1) {
    if (t < off) s[t] += s[t + off];
    __syncthreads();
  }
  if (t == 0) csum[b] = s[0];
}

__global__ __launch_bounds__(256) void scanbase_kernel(
    const int* __restrict__ csum, int* __restrict__ cbase) {
  __shared__ int s[256];
  int t = threadIdx.x;
  int v = csum[t];
  s[t] = v;
  __syncthreads();
  for (int off = 1; off < 256; off <<= 1) {
    int u = (t >= off) ? s[t - off] : 0;
    __syncthreads();
    s[t] += u;
    __syncthreads();
  }
  cbase[t] = s[t] - v;  // exclusive
}

__global__ __launch_bounds__(256) void scan2_kernel(
    const int* __restrict__ deg, const int* __restrict__ cbase,
    int* __restrict__ offs, int* __restrict__ cursor) {
  __shared__ int s[256];
  int b = blockIdx.x, t = threadIdx.x;
  int idx = b * SCAN_CHUNK + t;
  int val = (t < SCAN_CHUNK && idx < NNODES) ? deg[idx] : 0;
  s[t] = val;
  __syncthreads();
  for (int off = 1; off < 256; off <<= 1) {
    int u = (t >= off) ? s[t - off] : 0;
    __syncthreads();
    s[t] += u;
    __syncthreads();
  }
  if (t < SCAN_CHUNK && idx < NNODES) {
    int excl = cbase[b] + s[t] - val;
    offs[idx] = excl;
    cursor[idx] = excl;
  }
  if (b == 0 && t == 0) offs[NNODES] = NEDGES;
}

__global__ __launch_bounds__(256) void scatter_kernel(
    const int* __restrict__ eidx, const int* __restrict__ eattr,
    int* __restrict__ cursor, int* __restrict__ eout) {
  int e = blockIdx.x * 256 + threadIdx.x;
  if (e >= NEDGES) return;
  int d = eidx[NEDGES + e];
  int pos = atomicAdd(&cursor[d], 1);
  eout[pos] = eidx[e] | (eattr[e] << 16);  // src<65536, attr<4
}

// ===========================================================================
// Fused GINE layer. block = 128 (thread = channel), NB=8 nodes per group,
// 2 groups per block. Input BN (of previous layer) folded as affine.
// Gather: unroll-4 edge loop + preloaded self rows for memory-level parallelism.
// GEMM: ds_read_b128 broadcast of hA, coalesced dword weight loads.
// ===========================================================================
#define NB 8
#define GRID_GINE 3125  // * 2 groups = 6250 = 50000/8

__global__ __launch_bounds__(128, 6) void gine_mlp_kernel(
    const float* __restrict__ in, const float* __restrict__ instats,
    const float* __restrict__ gam, const float* __restrict__ bet,
    const int* __restrict__ offs, const int* __restrict__ eout,
    const float* __restrict__ edge_emb,
    const float* __restrict__ W1, const float* __restrict__ b1,
    const float* __restrict__ W2, const float* __restrict__ b2,
    float* __restrict__ h2, float* __restrict__ stats) {
  __shared__ __align__(16) float hA[NB * HID];
  __shared__ __align__(16) float hB[NB * HID];
  const int c = threadIdx.x;

  float scl = 1.0f, sh = 0.0f;
  if (instats) {
    float mu = instats[c] * (1.0f / NNODES);
    float var = instats[HID + c] * (1.0f / NNODES) - mu * mu;
    scl = gam[c] * rsqrtf(var + BN_EPS);
    sh = bet[c] - mu * scl;
  }
  // message = relu(scl * in[src] + (sh + edge_emb[attr]))
  float she0 = sh + edge_emb[0 * HID + c];
  float she1 = sh + edge_emb[1 * HID + c];
  float she2 = sh + edge_emb[2 * HID + c];
  float she3 = sh + edge_emb[3 * HID + c];
  float bias1 = b1[c];
  float bias2 = b2[c];

  float lsum = 0.0f, lsq = 0.0f;
  const float4* hA4 = (const float4*)hA;
  const float4* hB4 = (const float4*)hB;

  for (int g = blockIdx.x * 2; g < blockIdx.x * 2 + 2; g++) {
    int base = g * NB;
    // ---- preload self rows (8 loads in flight) ----
    float self[NB];
    #pragma unroll
    for (int n = 0; n < NB; n++) self[n] = in[(base + n) * HID + c];

    // ---- gather ----
    #pragma unroll
    for (int n = 0; n < NB; n++) {
      int node = base + n;
      float v = fmaf(self[n], scl, sh);
      int e = offs[node], e1 = offs[node + 1];
      for (; e + 4 <= e1; e += 4) {
        int p0 = eout[e], p1 = eout[e + 1], p2 = eout[e + 2], p3 = eout[e + 3];
        int s0 = p0 & 0xFFFF, a0 = p0 >> 16;
        int s1 = p1 & 0xFFFF, a1 = p1 >> 16;
        int s2 = p2 & 0xFFFF, a2 = p2 >> 16;
        int s3 = p3 & 0xFFFF, a3 = p3 >> 16;
        float x0 = in[s0 * HID + c];
        float x1 = in[s1 * HID + c];
        float x2 = in[s2 * HID + c];
        float x3 = in[s3 * HID + c];
        float e0s = (a0 == 0) ? she0 : (a0 == 1) ? she1 : (a0 == 2) ? she2 : she3;
        float e1s = (a1 == 0) ? she0 : (a1 == 1) ? she1 : (a1 == 2) ? she2 : she3;
        float e2s = (a2 == 0) ? she0 : (a2 == 1) ? she1 : (a2 == 2) ? she2 : she3;
        float e3s = (a3 == 0) ? she0 : (a3 == 1) ? she1 : (a3 == 2) ? she2 : she3;
        v += fmaxf(fmaf(x0, scl, e0s), 0.0f) + fmaxf(fmaf(x1, scl, e1s), 0.0f) +
             fmaxf(fmaf(x2, scl, e2s), 0.0f) + fmaxf(fmaf(x3, scl, e3s), 0.0f);
      }
      for (; e < e1; e++) {
        int p0 = eout[e];
        int s0 = p0 & 0xFFFF, a0 = p0 >> 16;
        float e0s = (a0 == 0) ? she0 : (a0 == 1) ? she1 : (a0 == 2) ? she2 : she3;
        v += fmaxf(fmaf(in[s0 * HID + c], scl, e0s), 0.0f);
      }
      hA[n * HID + c] = v;
    }
    __syncthreads();

    // ---- GEMM1: hB = relu(hA @ W1 + b1) ----
    float acc[NB];
    #pragma unroll
    for (int n = 0; n < NB; n++) acc[n] = bias1;
    for (int k4 = 0; k4 < HID / 4; k4++) {
      int k = k4 * 4;
      float w0 = W1[(k + 0) * HID + c];
      float w1 = W1[(k + 1) * HID + c];
      float w2 = W1[(k + 2) * HID + c];
      float w3 = W1[(k + 3) * HID + c];
      #pragma unroll
      for (int n = 0; n < NB; n++) {
        float4 a = hA4[n * (HID / 4) + k4];
        acc[n] = fmaf(a.x, w0, acc[n]);
        acc[n] = fmaf(a.y, w1, acc[n]);
        acc[n] = fmaf(a.z, w2, acc[n]);
        acc[n] = fmaf(a.w, w3, acc[n]);
      }
    }
    #pragma unroll
    for (int n = 0; n < NB; n++) hB[n * HID + c] = fmaxf(acc[n], 0.0f);
    __syncthreads();

    // ---- GEMM2: h2 = relu(hB @ W2 + b2) ----
    #pragma unroll
    for (int n = 0; n < NB; n++) acc[n] = bias2;
    for (int k4 = 0; k4 < HID / 4; k4++) {
      int k = k4 * 4;
      float w0 = W2[(k + 0) * HID + c];
      float w1 = W2[(k + 1) * HID + c];
      float w2 = W2[(k + 2) * HID + c];
      float w3 = W2[(k + 3) * HID + c];
      #pragma unroll
      for (int n = 0; n < NB; n++) {
        float4 a = hB4[n * (HID / 4) + k4];
        acc[n] = fmaf(a.x, w0, acc[n]);
        acc[n] = fmaf(a.y, w1, acc[n]);
        acc[n] = fmaf(a.z, w2, acc[n]);
        acc[n] = fmaf(a.w, w3, acc[n]);
      }
    }
    #pragma unroll
    for (int n = 0; n < NB; n++) {
      float v = fmaxf(acc[n], 0.0f);
      h2[(base + n) * HID + c] = v;
      lsum += v;
      lsq += v * v;
    }
    // no barrier needed here: next gather writes only hA, and both waves have
    // passed the GEMM1->GEMM2 barrier (done reading hA); hB of next group is
    // written only after the next gather barrier, when GEMM2 reads are done.
  }
  unsafeAtomicAdd(&stats[c], lsum);
  unsafeAtomicAdd(&stats[HID + c], lsq);
}

// ---------------------------------------------------------------------------
// Final BN + global_add_pool fused (batch sorted -> run-length accumulate).
#define PNB 100
__global__ __launch_bounds__(128) void bn_pool_kernel(
    const float* __restrict__ h, const float* __restrict__ stats,
    const float* __restrict__ gam, const float* __restrict__ bet,
    const int* __restrict__ batch, float* __restrict__ out) {
  int c = threadIdx.x;
  float mu = stats[c] * (1.0f / NNODES);
  float var = stats[HID + c] * (1.0f / NNODES) - mu * mu;
  float scl = gam[c] * rsqrtf(var + BN_EPS);
  float sh = bet[c] - mu * scl;
  int n0 = blockIdx.x * PNB;
  int n1 = min(n0 + PNB, NNODES);
  if (n0 >= NNODES) return;
  int cur = batch[n0];
  float acc = 0.0f;
  for (int n = n0; n < n1; n++) {
    int g = batch[n];
    if (g != cur) {
      unsafeAtomicAdd(&out[cur * HID + c], acc);
      acc = 0.0f;
      cur = g;
    }
    acc += fmaf(h[n * HID + c], scl, sh);
  }
  unsafeAtomicAdd(&out[cur * HID + c], acc);
}

// ---------------------------------------------------------------------------
extern "C" void kernel_launch(void* const* d_in, const int* in_sizes, int n_in,
                              void* d_out, int out_size, void* d_ws, size_t ws_size,
                              hipStream_t stream) {
  const int* x_idx = (const int*)d_in[0];
  const int* eidx = (const int*)d_in[1];   // [2, E]: src row then dst row
  const int* eattr = (const int*)d_in[2];
  const int* batch = (const int*)d_in[3];
  const float* node_emb = (const float*)d_in[4];
  const float* edge_emb = (const float*)d_in[5];
  const float* W1 = (const float*)d_in[6];
  const float* b1 = (const float*)d_in[7];
  const float* W2 = (const float*)d_in[8];
  const float* b2 = (const float*)d_in[9];
  const float* bn_g = (const float*)d_in[10];
  const float* bn_b = (const float*)d_in[11];
  float* out = (float*)d_out;

  const size_t nfeat = (size_t)NNODES * HID;
  float* x = (float*)d_ws;              // [N,H]   (layer-1 output reuses this)
  float* h2a = x + nfeat;               // [N,H]
  float* stats0 = h2a + nfeat;          // [2,H]
  float* stats1 = stats0 + 2 * HID;     // [2,H]
  int* deg = (int*)(stats1 + 2 * HID);  // [N]   (zeroed together with stats)
  int* offs = deg + NNODES;             // [N+1]
  int* cursor = offs + (NNODES + 1);    // [N]
  int* csum = cursor + NNODES;          // [256]
  int* cbase = csum + 256;              // [256]
  int* eout = cbase + 256;              // [E]
  size_t needed = (size_t)((char*)(eout + NEDGES) - (char*)d_ws);
  if (ws_size < needed) return;  // would fail validation loudly, not corrupt

  hipMemsetAsync(d_out, 0, (size_t)NGRAPHS * HID * sizeof(float), stream);
  // zero stats0, stats1, deg in one shot (contiguous)
  hipMemsetAsync(stats0, 0, (4 * HID + NNODES) * sizeof(int), stream);

  prep_kernel<<<1024, 256, 0, stream>>>(x_idx, node_emb, x, eidx, deg);
  chunksum_kernel<<<256, 256, 0, stream>>>(deg, csum);
  scanbase_kernel<<<1, 256, 0, stream>>>(csum, cbase);
  scan2_kernel<<<256, 256, 0, stream>>>(deg, cbase, offs, cursor);
  scatter_kernel<<<(NEDGES + 255) / 256, 256, 0, stream>>>(eidx, eattr, cursor,
                                                           eout);

  // layer 0: in = x (identity affine), out -> h2a, stats -> stats0
  gine_mlp_kernel<<<GRID_GINE, 128, 0, stream>>>(
      x, nullptr, nullptr, nullptr, offs, eout, edge_emb,
      W1, b1, W2, b2, h2a, stats0);
  // layer 1: in = h2a with BN(layer0) folded, out -> x, stats -> stats1
  gine_mlp_kernel<<<GRID_GINE, 128, 0, stream>>>(
      h2a, stats0, bn_g, bn_b, offs, eout, edge_emb,
      W1 + (size_t)HID * HID, b1 + HID, W2 + (size_t)HID * HID, b2 + HID,
      x, stats1);
  // final BN + pool fused
  bn_pool_kernel<<<(NNODES + PNB - 1) / PNB, 128, 0, stream>>>(
      x, stats1, bn_g + HID, bn_b + HID, batch, out);
}

// Round 5
// 530.515 us; speedup vs baseline: 1.5586x; 1.0682x over previous
//
#include <hip/hip_runtime.h>
#include <hip/hip_bf16.h>

#define HID 128
#define NNODES 50000
#define NEDGES 800000
#define NGRAPHS 64
#define BN_EPS 1e-5f
#define SCAN_CHUNK 196  // 256*196 = 50176 >= 50000

static __device__ __forceinline__ unsigned short f2bf(float v) {
  __hip_bfloat16 b = __float2bfloat16(v);  // round-to-nearest
  return *reinterpret_cast<unsigned short*>(&b);
}
static __device__ __forceinline__ float bf2f(unsigned short u) {
  return __uint_as_float(((unsigned)u) << 16);
}

// ===========================================================================
// prep: xbf = bf16(node_emb[x_idx]) + in-degree histogram
// ===========================================================================
__global__ __launch_bounds__(256) void prep_kernel(
    const int* __restrict__ x_idx, const float* __restrict__ node_emb,
    unsigned short* __restrict__ xbf, const int* __restrict__ eidx,
    int* __restrict__ deg) {
  int i = blockIdx.x * 256 + threadIdx.x;
  int stride = gridDim.x * 256;
  for (int t = i; t < NNODES * HID; t += stride) {
    int n = t >> 7;
    int cc = t & 127;
    xbf[t] = f2bf(node_emb[x_idx[n] * HID + cc]);
  }
  for (int t = i; t < NEDGES; t += stride)
    atomicAdd(&deg[eidx[NEDGES + t]], 1);
}

// ===========================================================================
// CSR build (3-pass coalesced scan + scatter)
// ===========================================================================
__global__ __launch_bounds__(256) void chunksum_kernel(
    const int* __restrict__ deg, int* __restrict__ csum) {
  __shared__ int s[256];
  int b = blockIdx.x, t = threadIdx.x;
  int idx = b * SCAN_CHUNK + t;
  s[t] = (t < SCAN_CHUNK && idx < NNODES) ? deg[idx] : 0;
  __syncthreads();
  for (int off = 128; off > 0; off >>= 1) {
    if (t < off) s[t] += s[t + off];
    __syncthreads();
  }
  if (t == 0) csum[b] = s[0];
}

__global__ __launch_bounds__(256) void scanbase_kernel(
    const int* __restrict__ csum, int* __restrict__ cbase) {
  __shared__ int s[256];
  int t = threadIdx.x;
  int v = csum[t];
  s[t] = v;
  __syncthreads();
  for (int off = 1; off < 256; off <<= 1) {
    int u = (t >= off) ? s[t - off] : 0;
    __syncthreads();
    s[t] += u;
    __syncthreads();
  }
  cbase[t] = s[t] - v;  // exclusive
}

__global__ __launch_bounds__(256) void scan2_kernel(
    const int* __restrict__ deg, const int* __restrict__ cbase,
    int* __restrict__ offs, int* __restrict__ cursor) {
  __shared__ int s[256];
  int b = blockIdx.x, t = threadIdx.x;
  int idx = b * SCAN_CHUNK + t;
  int val = (t < SCAN_CHUNK && idx < NNODES) ? deg[idx] : 0;
  s[t] = val;
  __syncthreads();
  for (int off = 1; off < 256; off <<= 1) {
    int u = (t >= off) ? s[t - off] : 0;
    __syncthreads();
    s[t] += u;
    __syncthreads();
  }
  if (t < SCAN_CHUNK && idx < NNODES) {
    int excl = cbase[b] + s[t] - val;
    offs[idx] = excl;
    cursor[idx] = excl;
  }
  if (b == 0 && t == 0) offs[NNODES] = NEDGES;
}

__global__ __launch_bounds__(256) void scatter_kernel(
    const int* __restrict__ eidx, const int* __restrict__ eattr,
    int* __restrict__ cursor, int* __restrict__ eout) {
  int e = blockIdx.x * 256 + threadIdx.x;
  if (e >= NEDGES) return;
  int d = eidx[NEDGES + e];
  int pos = atomicAdd(&cursor[d], 1);
  eout[pos] = eidx[e] | (eattr[e] << 16);  // src<65536, attr<4
}

// ===========================================================================
// Fused GINE layer. block = 128 (thread = channel), NB=8 nodes/group,
// 2 groups/block. Node features in bf16 (halves gather traffic).
// Input BN folded as per-channel affine. Optional outputs:
//   out_bf  : bf16 h2 (layer 0 -> feeds layer 1)
//   gpool   : per-graph raw sums of h2 (layer 1 -> feeds finish kernel)
// ===========================================================================
#define NB 8
#define GRID_GINE 3125  // * 2 groups = 6250 = 50000/8

__global__ __launch_bounds__(128, 8) void gine_mlp_kernel(
    const unsigned short* __restrict__ in_bf, const float* __restrict__ instats,
    const float* __restrict__ gam, const float* __restrict__ bet,
    const int* __restrict__ offs, const int* __restrict__ eout,
    const float* __restrict__ edge_emb,
    const float* __restrict__ W1, const float* __restrict__ b1,
    const float* __restrict__ W2, const float* __restrict__ b2,
    unsigned short* __restrict__ out_bf, float* __restrict__ stats,
    const int* __restrict__ batch, float* __restrict__ gpool) {
  __shared__ __align__(16) float hA[NB * HID];
  __shared__ __align__(16) float hB[NB * HID];
  const int c = threadIdx.x;

  float scl = 1.0f, sh = 0.0f;
  if (instats) {
    float mu = instats[c] * (1.0f / NNODES);
    float var = instats[HID + c] * (1.0f / NNODES) - mu * mu;
    scl = gam[c] * rsqrtf(var + BN_EPS);
    sh = bet[c] - mu * scl;
  }
  // message = relu(scl * in[src] + (sh + edge_emb[attr]))
  float she0 = sh + edge_emb[0 * HID + c];
  float she1 = sh + edge_emb[1 * HID + c];
  float she2 = sh + edge_emb[2 * HID + c];
  float she3 = sh + edge_emb[3 * HID + c];
  float bias1 = b1[c];
  float bias2 = b2[c];

  float lsum = 0.0f, lsq = 0.0f;
  int curg = -1;        // pooling run-length state (layer 1 only)
  float pacc = 0.0f;
  const float4* hA4 = (const float4*)hA;
  const float4* hB4 = (const float4*)hB;

  for (int g = blockIdx.x * 2; g < blockIdx.x * 2 + 2; g++) {
    int base = g * NB;
    // ---- preload self rows ----
    float self[NB];
    #pragma unroll
    for (int n = 0; n < NB; n++) self[n] = bf2f(in_bf[(base + n) * HID + c]);

    // ---- gather ----
    #pragma unroll
    for (int n = 0; n < NB; n++) {
      int node = base + n;
      float v = fmaf(self[n], scl, sh);
      int e = offs[node], e1 = offs[node + 1];
      for (; e + 4 <= e1; e += 4) {
        int p0 = eout[e], p1 = eout[e + 1], p2 = eout[e + 2], p3 = eout[e + 3];
        int s0 = p0 & 0xFFFF, a0 = p0 >> 16;
        int s1 = p1 & 0xFFFF, a1 = p1 >> 16;
        int s2 = p2 & 0xFFFF, a2 = p2 >> 16;
        int s3 = p3 & 0xFFFF, a3 = p3 >> 16;
        float x0 = bf2f(in_bf[s0 * HID + c]);
        float x1 = bf2f(in_bf[s1 * HID + c]);
        float x2 = bf2f(in_bf[s2 * HID + c]);
        float x3 = bf2f(in_bf[s3 * HID + c]);
        float e0s = (a0 == 0) ? she0 : (a0 == 1) ? she1 : (a0 == 2) ? she2 : she3;
        float e1s = (a1 == 0) ? she0 : (a1 == 1) ? she1 : (a1 == 2) ? she2 : she3;
        float e2s = (a2 == 0) ? she0 : (a2 == 1) ? she1 : (a2 == 2) ? she2 : she3;
        float e3s = (a3 == 0) ? she0 : (a3 == 1) ? she1 : (a3 == 2) ? she2 : she3;
        v += fmaxf(fmaf(x0, scl, e0s), 0.0f) + fmaxf(fmaf(x1, scl, e1s), 0.0f) +
             fmaxf(fmaf(x2, scl, e2s), 0.0f) + fmaxf(fmaf(x3, scl, e3s), 0.0f);
      }
      for (; e < e1; e++) {
        int p0 = eout[e];
        int s0 = p0 & 0xFFFF, a0 = p0 >> 16;
        float e0s = (a0 == 0) ? she0 : (a0 == 1) ? she1 : (a0 == 2) ? she2 : she3;
        v += fmaxf(fmaf(bf2f(in_bf[s0 * HID + c]), scl, e0s), 0.0f);
      }
      hA[n * HID + c] = v;
    }
    __syncthreads();

    // ---- GEMM1: hB = relu(hA @ W1 + b1) ----
    float acc[NB];
    #pragma unroll
    for (int n = 0; n < NB; n++) acc[n] = bias1;
    for (int k4 = 0; k4 < HID / 4; k4++) {
      int k = k4 * 4;
      float w0 = W1[(k + 0) * HID + c];
      float w1 = W1[(k + 1) * HID + c];
      float w2 = W1[(k + 2) * HID + c];
      float w3 = W1[(k + 3) * HID + c];
      #pragma unroll
      for (int n = 0; n < NB; n++) {
        float4 a = hA4[n * (HID / 4) + k4];
        acc[n] = fmaf(a.x, w0, acc[n]);
        acc[n] = fmaf(a.y, w1, acc[n]);
        acc[n] = fmaf(a.z, w2, acc[n]);
        acc[n] = fmaf(a.w, w3, acc[n]);
      }
    }
    #pragma unroll
    for (int n = 0; n < NB; n++) hB[n * HID + c] = fmaxf(acc[n], 0.0f);
    __syncthreads();

    // ---- GEMM2: h2 = relu(hB @ W2 + b2) ----
    #pragma unroll
    for (int n = 0; n < NB; n++) acc[n] = bias2;
    for (int k4 = 0; k4 < HID / 4; k4++) {
      int k = k4 * 4;
      float w0 = W2[(k + 0) * HID + c];
      float w1 = W2[(k + 1) * HID + c];
      float w2 = W2[(k + 2) * HID + c];
      float w3 = W2[(k + 3) * HID + c];
      #pragma unroll
      for (int n = 0; n < NB; n++) {
        float4 a = hB4[n * (HID / 4) + k4];
        acc[n] = fmaf(a.x, w0, acc[n]);
        acc[n] = fmaf(a.y, w1, acc[n]);
        acc[n] = fmaf(a.z, w2, acc[n]);
        acc[n] = fmaf(a.w, w3, acc[n]);
      }
    }
    #pragma unroll
    for (int n = 0; n < NB; n++) {
      int node = base + n;
      float v = fmaxf(acc[n], 0.0f);
      lsum += v;
      lsq += v * v;
      if (out_bf) out_bf[node * HID + c] = f2bf(v);
      if (gpool) {
        int bg = batch[node];
        if (bg != curg) {
          if (curg >= 0) unsafeAtomicAdd(&gpool[curg * HID + c], pacc);
          curg = bg;
          pacc = 0.0f;
        }
        pacc += v;
      }
    }
    // no barrier needed: next gather writes only hA, and all waves passed the
    // GEMM1->GEMM2 barrier (done reading hA); hB is rewritten only after the
    // next gather barrier, by which time GEMM2 reads are done.
  }
  if (gpool && curg >= 0) unsafeAtomicAdd(&gpool[curg * HID + c], pacc);
  unsafeAtomicAdd(&stats[c], lsum);
  unsafeAtomicAdd(&stats[HID + c], lsq);
}

// ---------------------------------------------------------------------------
// out[g,c] = scl_c * gpool[g,c] + cnt_g * sh_c   (BN is affine -> commutes
// with segment_sum). cnt_g via binary search on sorted batch.
__device__ __forceinline__ int lbound(const int* __restrict__ arr, int n,
                                      int key) {
  int lo = 0, hi = n;
  while (lo < hi) {
    int mid = (lo + hi) >> 1;
    if (arr[mid] < key) lo = mid + 1; else hi = mid;
  }
  return lo;
}

__global__ __launch_bounds__(128) void finish_kernel(
    const float* __restrict__ gpool, const float* __restrict__ stats,
    const float* __restrict__ gam, const float* __restrict__ bet,
    const int* __restrict__ batch, float* __restrict__ out) {
  __shared__ int cnt_s;
  int g = blockIdx.x, c = threadIdx.x;
  if (c == 0)
    cnt_s = lbound(batch, NNODES, g + 1) - lbound(batch, NNODES, g);
  __syncthreads();
  float mu = stats[c] * (1.0f / NNODES);
  float var = stats[HID + c] * (1.0f / NNODES) - mu * mu;
  float scl = gam[c] * rsqrtf(var + BN_EPS);
  float sh = bet[c] - mu * scl;
  out[g * HID + c] = fmaf(gpool[g * HID + c], scl, (float)cnt_s * sh);
}

// ---------------------------------------------------------------------------
extern "C" void kernel_launch(void* const* d_in, const int* in_sizes, int n_in,
                              void* d_out, int out_size, void* d_ws, size_t ws_size,
                              hipStream_t stream) {
  const int* x_idx = (const int*)d_in[0];
  const int* eidx = (const int*)d_in[1];   // [2, E]: src row then dst row
  const int* eattr = (const int*)d_in[2];
  const int* batch = (const int*)d_in[3];
  const float* node_emb = (const float*)d_in[4];
  const float* edge_emb = (const float*)d_in[5];
  const float* W1 = (const float*)d_in[6];
  const float* b1 = (const float*)d_in[7];
  const float* W2 = (const float*)d_in[8];
  const float* b2 = (const float*)d_in[9];
  const float* bn_g = (const float*)d_in[10];
  const float* bn_b = (const float*)d_in[11];
  float* out = (float*)d_out;

  const size_t nfeat = (size_t)NNODES * HID;
  unsigned short* xbf = (unsigned short*)d_ws;   // [N,H] bf16
  unsigned short* h2abf = xbf + nfeat;           // [N,H] bf16
  float* stats0 = (float*)(h2abf + nfeat);       // [2,H]
  float* stats1 = stats0 + 2 * HID;              // [2,H]
  float* gpool = stats1 + 2 * HID;               // [G,H]
  int* deg = (int*)(gpool + NGRAPHS * HID);      // [N]
  int* offs = deg + NNODES;                      // [N+1]
  int* cursor = offs + (NNODES + 1);             // [N]
  int* csum = cursor + NNODES;                   // [256]
  int* cbase = csum + 256;                       // [256]
  int* eout = cbase + 256;                       // [E]
  size_t needed = (size_t)((char*)(eout + NEDGES) - (char*)d_ws);
  if (ws_size < needed) return;  // fails validation loudly, doesn't corrupt

  // zero stats0, stats1, gpool, deg in one shot (contiguous)
  hipMemsetAsync(stats0, 0, (4 * HID + NGRAPHS * HID + NNODES) * sizeof(int),
                 stream);

  prep_kernel<<<1024, 256, 0, stream>>>(x_idx, node_emb, xbf, eidx, deg);
  chunksum_kernel<<<256, 256, 0, stream>>>(deg, csum);
  scanbase_kernel<<<1, 256, 0, stream>>>(csum, cbase);
  scan2_kernel<<<256, 256, 0, stream>>>(deg, cbase, offs, cursor);
  scatter_kernel<<<(NEDGES + 255) / 256, 256, 0, stream>>>(eidx, eattr, cursor,
                                                           eout);

  // layer 0: in = xbf (identity affine), out -> h2abf (bf16), stats0
  gine_mlp_kernel<<<GRID_GINE, 128, 0, stream>>>(
      xbf, nullptr, nullptr, nullptr, offs, eout, edge_emb,
      W1, b1, W2, b2, h2abf, stats0, nullptr, nullptr);
  // layer 1: in = h2abf with BN(layer0) folded, out -> per-graph sums + stats1
  gine_mlp_kernel<<<GRID_GINE, 128, 0, stream>>>(
      h2abf, stats0, bn_g, bn_b, offs, eout, edge_emb,
      W1 + (size_t)HID * HID, b1 + HID, W2 + (size_t)HID * HID, b2 + HID,
      nullptr, stats1, batch, gpool);
  // final: out = scl*gpool + cnt*sh
  finish_kernel<<<NGRAPHS, 128, 0, stream>>>(gpool, stats1, bn_g + HID,
                                             bn_b + HID, batch, out);
}